// Round 3
// baseline (3551.830 us; speedup 1.0000x reference)
//
#include <hip/hip_runtime.h>
#include <math.h>

typedef unsigned int u32;

#define NT   262144      // tokens
#define CI   96
#define CO   96
#define HID  192
#define NE   8
#define NB   4
#define CAP  40960       // int(NT/NE*1.25)
#define KIN  97          // C_IN + 1 (band feature)

// ---------------- workspace layout (bytes) ----------------
#define WS_AFF    0ull                 // [NE][NT] f32             8,388,608
#define WS_SEL    8388608ull           // [NE*4][CAP] u32          5,242,880
#define WS_W1E    13631488ull          // [NE*4][97][192] f32      2,383,872
#define WS_W2E    16015360ull          // [NE*4][192][96] f32      2,359,296
#define WS_H1     18374656ull          // [NE][65536] u32          2,097,152   <- zero from here
#define WS_H2     20471808ull          // [NE][65536] u32          2,097,152
#define WS_HI1    22568960ull          // [NE][512] u32            16,384
#define WS_HI2    22585344ull          // [NE][512] u32            16,384
#define WS_ST     22601728ull          // stats                    1,024
#define WS_WS     22602752ull          // w_sums [NT] f32          1,048,576
#define WS_END    23651328ull

// stats u32 indices
#define ST_VMAX  0
#define ST_BH    8
#define ST_KR1   16
#define ST_T     24
#define ST_NEED  32
#define ST_ITH   40     // 0xFFFFFFFF = pending, 0x7FFFFFFF = all ties selected
#define ST_BI    48
#define ST_KRI   56
#define ST_CNT   64     // [NE*4] band-bucket counters
#define ST_VMF   96     // f32
#define ST_SE    104    // f32
// byte 448: double sum_s ; byte 456: double sum_s2

__device__ __forceinline__ u32 ou32(float f) {
  u32 u = __float_as_uint(f);
  return (u & 0x80000000u) ? ~u : (u | 0x80000000u);
}
__device__ __forceinline__ float ou2f(u32 o) {
  u32 u = (o & 0x80000000u) ? (o & 0x7FFFFFFFu) : ~o;
  return __uint_as_float(u);
}
__device__ __forceinline__ float gelu_f(float x) {
  return 0.5f * x * (1.f + erff(x * 0.70710678118654752440f));
}
__device__ __forceinline__ float waveRed(float v) {
  #pragma unroll
  for (int o = 32; o > 0; o >>= 1) v += __shfl_down(v, o);
  return v;
}

// ---------------- merged LoRA weights: W{1,2}eff[e][b] ----------------
__global__ void k_eff(const float* __restrict__ W1, const float* __restrict__ A1,
                      const float* __restrict__ B1, const float* __restrict__ W2,
                      const float* __restrict__ A2, const float* __restrict__ B2,
                      char* __restrict__ wsc) {
  const int eb = blockIdx.x, e = eb >> 2;
  __shared__ float a1s[KIN * 8], b1s[8 * HID], a2s[HID * 8], b2s[8 * CO];
  const int tid = threadIdx.x;
  for (int i = tid; i < KIN * 8; i += 256) a1s[i] = A1[(size_t)eb * KIN * 8 + i];
  for (int i = tid; i < 8 * HID; i += 256) b1s[i] = B1[(size_t)eb * 8 * HID + i];
  for (int i = tid; i < HID * 8; i += 256) a2s[i] = A2[(size_t)eb * HID * 8 + i];
  for (int i = tid; i < 8 * CO;  i += 256) b2s[i] = B2[(size_t)eb * 8 * CO + i];
  __syncthreads();
  float* w1o = (float*)(wsc + WS_W1E) + (size_t)eb * KIN * HID;
  for (int i = tid; i < KIN * HID; i += 256) {
    const int k = i / HID, n = i - k * HID;
    float acc = W1[(size_t)e * KIN * HID + i];
    #pragma unroll
    for (int r = 0; r < 8; ++r) acc += 2.0f * a1s[k * 8 + r] * b1s[r * HID + n];
    w1o[i] = acc;
  }
  float* w2o = (float*)(wsc + WS_W2E) + (size_t)eb * HID * CO;
  for (int i = tid; i < HID * CO; i += 256) {
    const int k = i / CO, n = i - k * CO;
    float acc = W2[(size_t)e * HID * CO + i];
    #pragma unroll
    for (int r = 0; r < 8; ++r) acc += 2.0f * a2s[k * 8 + r] * b2s[r * CO + n];
    w2o[i] = acc;
  }
}

// ------- complexity head + affinity + hist1 + vmax + var sums (fused) -------
__global__ __launch_bounds__(256) void k_aff(const float* __restrict__ x,
    const float* __restrict__ Wg, const float* __restrict__ lam,
    const float* __restrict__ cw1, const float* __restrict__ cb1,
    const float* __restrict__ cw2, const float* __restrict__ cb2,
    char* __restrict__ wsc) {
  const int t = blockIdx.x * 256 + threadIdx.x;
  float th[32];
  #pragma unroll
  for (int j = 0; j < 32; ++j) th[j] = cb1[j];
  float av[8];
  #pragma unroll
  for (int e = 0; e < 8; ++e) av[e] = 0.f;
  const float* xr = x + (size_t)t * CI;
  for (int c = 0; c < 96; c += 4) {
    const float4 xv = *(const float4*)(xr + c);
    const float xs[4] = {xv.x, xv.y, xv.z, xv.w};
    #pragma unroll
    for (int jj = 0; jj < 4; ++jj) {
      const float xc = xs[jj];
      const float* w = cw1 + (c + jj) * 32;
      #pragma unroll
      for (int j = 0; j < 32; ++j) th[j] = fmaf(xc, w[j], th[j]);
      const float* g = Wg + (c + jj) * 8;
      #pragma unroll
      for (int e = 0; e < 8; ++e) av[e] = fmaf(xc, g[e], av[e]);
    }
  }
  float cs = cb2[0];
  #pragma unroll
  for (int j = 0; j < 32; ++j) cs = fmaf(gelu_f(th[j]), cw2[j], cs);
  const float lamv = lam[0];

  float* aff = (float*)(wsc + WS_AFF);
  u32* h1 = (u32*)(wsc + WS_H1);
  __shared__ u32 bmax[8];
  if (threadIdx.x < 8) bmax[threadIdx.x] = 0u;
  __syncthreads();
  #pragma unroll
  for (int e = 0; e < 8; ++e) {
    const float a = fmaf(lamv, cs, av[e]);
    aff[(size_t)e * NT + t] = a;
    const u32 o = ou32(a);
    atomicMax(&bmax[e], o);
    atomicAdd(&h1[(e << 16) + (o >> 16)], 1u);
  }
  // variance sums (double precision across blocks)
  float s1 = waveRed(cs), s2 = waveRed(cs * cs);
  __shared__ float r1[4], r2[4];
  if ((threadIdx.x & 63) == 0) { r1[threadIdx.x >> 6] = s1; r2[threadIdx.x >> 6] = s2; }
  __syncthreads();
  if (threadIdx.x < 8)
    atomicMax((u32*)(wsc + WS_ST) + ST_VMAX + threadIdx.x, bmax[threadIdx.x]);
  if (threadIdx.x == 0) {
    atomicAdd((double*)(wsc + WS_ST + 448), (double)r1[0] + r1[1] + r1[2] + r1[3]);
    atomicAdd((double*)(wsc + WS_ST + 456), (double)r2[0] + r2[1] + r2[2] + r2[3]);
  }
}

// ---------------- radix-select scans ----------------
__global__ void k_scan1(char* __restrict__ wsc) {
  const int e = blockIdx.x;
  u32* SU = (u32*)(wsc + WS_ST);
  const u32* h = (const u32*)(wsc + WS_H1) + ((size_t)e << 16);
  __shared__ u32 part[256]; __shared__ u32 sfx[257];
  u32 s = 0; const int base = threadIdx.x << 8;
  for (int i = 0; i < 256; ++i) s += h[base + i];
  part[threadIdx.x] = s;
  __syncthreads();
  if (threadIdx.x == 0) {
    u32 run = 0; sfx[256] = 0;
    for (int tt = 255; tt >= 0; --tt) { run += part[tt]; sfx[tt] = run; }
  }
  __syncthreads();
  const u32 K = CAP;
  if (sfx[threadIdx.x] >= K && sfx[threadIdx.x + 1] < K) {
    u32 run = sfx[threadIdx.x + 1];
    for (int bin = base + 255; bin >= base; --bin) {
      const u32 c = h[bin];
      if (run + c >= K) { SU[ST_BH + e] = (u32)bin; SU[ST_KR1 + e] = K - run; break; }
      run += c;
    }
  }
}

__global__ void k_hist2(char* __restrict__ wsc) {
  const long i = (long)blockIdx.x * 256 + threadIdx.x;
  const int e = (int)(i >> 18);
  const u32* SU = (const u32*)(wsc + WS_ST);
  const u32 o = ou32(((const float*)(wsc + WS_AFF))[i]);
  if ((o >> 16) == SU[ST_BH + e])
    atomicAdd((u32*)(wsc + WS_H2) + ((size_t)e << 16) + (o & 0xFFFFu), 1u);
}

__global__ void k_scan2(char* __restrict__ wsc) {
  const int e = blockIdx.x;
  u32* SU = (u32*)(wsc + WS_ST);
  float* SF = (float*)(wsc + WS_ST);
  const u32* h = (const u32*)(wsc + WS_H2) + ((size_t)e << 16);
  __shared__ u32 part[256]; __shared__ u32 sfx[257];
  u32 s = 0; const int base = threadIdx.x << 8;
  for (int i = 0; i < 256; ++i) s += h[base + i];
  part[threadIdx.x] = s;
  __syncthreads();
  if (threadIdx.x == 0) {
    u32 run = 0; sfx[256] = 0;
    for (int tt = 255; tt >= 0; --tt) { run += part[tt]; sfx[tt] = run; }
    SF[ST_VMF + e] = ou2f(SU[ST_VMAX + e]);
  }
  __syncthreads();
  const u32 K = SU[ST_KR1 + e];
  if (sfx[threadIdx.x] >= K && sfx[threadIdx.x + 1] < K) {
    u32 run = sfx[threadIdx.x + 1];
    for (int bin = base + 255; bin >= base; --bin) {
      const u32 c = h[bin];
      if (run + c >= K) {
        const u32 need = K - run;
        SU[ST_T + e] = (SU[ST_BH + e] << 16) | (u32)bin;
        SU[ST_NEED + e] = need;
        SU[ST_ITH + e] = (need == c) ? 0x7FFFFFFFu : 0xFFFFFFFFu;
        break;
      }
      run += c;
    }
  }
}

// tie-at-threshold: select 'need' smallest token indices among ties
__global__ void k_histI1(char* __restrict__ wsc) {
  const long i = (long)blockIdx.x * 256 + threadIdx.x;
  const int e = (int)(i >> 18);
  const u32* SU = (const u32*)(wsc + WS_ST);
  if (SU[ST_ITH + e] != 0xFFFFFFFFu) return;
  const u32 o = ou32(((const float*)(wsc + WS_AFF))[i]);
  if (o == SU[ST_T + e]) {
    const int n = (int)(i & (NT - 1));
    atomicAdd((u32*)(wsc + WS_HI1) + e * 512 + (n >> 9), 1u);
  }
}
__global__ void k_scanI1(char* __restrict__ wsc) {
  const int e = blockIdx.x;
  u32* SU = (u32*)(wsc + WS_ST);
  if (threadIdx.x != 0 || SU[ST_ITH + e] != 0xFFFFFFFFu) return;
  const u32* h = (const u32*)(wsc + WS_HI1) + e * 512;
  const u32 need = SU[ST_NEED + e];
  u32 run = 0;
  for (int bk = 0; bk < 512; ++bk) {
    const u32 c = h[bk];
    if (run + c >= need) { SU[ST_BI + e] = (u32)bk; SU[ST_KRI + e] = need - run; break; }
    run += c;
  }
}
__global__ void k_histI2(char* __restrict__ wsc) {
  const long i = (long)blockIdx.x * 256 + threadIdx.x;
  const int e = (int)(i >> 18);
  const u32* SU = (const u32*)(wsc + WS_ST);
  if (SU[ST_ITH + e] != 0xFFFFFFFFu) return;
  const u32 o = ou32(((const float*)(wsc + WS_AFF))[i]);
  const int n = (int)(i & (NT - 1));
  if (o == SU[ST_T + e] && (u32)(n >> 9) == SU[ST_BI + e])
    atomicAdd((u32*)(wsc + WS_HI2) + e * 512 + (n & 511), 1u);
}
__global__ void k_scanI2(char* __restrict__ wsc) {
  const int e = blockIdx.x;
  u32* SU = (u32*)(wsc + WS_ST);
  if (threadIdx.x != 0 || SU[ST_ITH + e] != 0xFFFFFFFFu) return;
  const u32* h = (const u32*)(wsc + WS_HI2) + e * 512;
  const u32 kri = SU[ST_KRI + e];
  u32 run = 0;
  for (int j = 0; j < 512; ++j) {
    const u32 c = h[j];
    if (run + c >= kri) { SU[ST_ITH + e] = (SU[ST_BI + e] << 9) | (u32)j; break; }
    run += c;
  }
}

// -------- compaction into band buckets + softmax denominator --------
__global__ void k_compact(const int* __restrict__ band, char* __restrict__ wsc) {
  const int e = blockIdx.x >> 10;
  const int n = ((blockIdx.x & 1023) << 8) + threadIdx.x;
  u32* SU = (u32*)(wsc + WS_ST);
  float* SF = (float*)(wsc + WS_ST);
  const float a = ((const float*)(wsc + WS_AFF))[(size_t)e * NT + n];
  const u32 o = ou32(a);
  const u32 T = SU[ST_T + e];
  float pe = 0.f;
  if (o > T || (o == T && (u32)n <= SU[ST_ITH + e])) {
    const int bd = band[n];
    const u32 pos = atomicAdd(&SU[ST_CNT + (e << 2) + bd], 1u);
    ((u32*)(wsc + WS_SEL))[(size_t)((e << 2) + bd) * CAP + pos] = (u32)n;
    pe = expf(a - SF[ST_VMF + e]);
  }
  float s = waveRed(pe);
  __shared__ float r[4];
  if ((threadIdx.x & 63) == 0) r[threadIdx.x >> 6] = s;
  __syncthreads();
  if (threadIdx.x == 0) unsafeAtomicAdd(&SF[ST_SE + e], r[0] + r[1] + r[2] + r[3]);
}

// ---------------- fused expert MLP (band-uniform blocks) ----------------
union SmemU {
  struct { float A[2 * 33 * 128]; float B[2 * 33 * 192]; } p1;   // 84,480 B
  struct { float hT[192 * 128];   float w2[2 * 32 * 96]; } p2;   // 122,880 B
};

__global__ __launch_bounds__(256, 1) void k_mlp(
    const float* __restrict__ x, const float* __restrict__ eb1,
    const float* __restrict__ eb2, char* __restrict__ wsc, float* __restrict__ dout) {
  const int bx = blockIdx.x;
  const int e = bx / 1280;
  const int rem = bx - e * 1280;
  const int b = rem / 320;
  const int tile = rem - b * 320;

  u32* SU = (u32*)(wsc + WS_ST);
  const int cnt = (int)SU[ST_CNT + (e << 2) + b];
  const int slot0 = tile << 7;
  if (slot0 >= cnt) return;
  const int valid = min(128, cnt - slot0);

  const float* SF = (const float*)(wsc + WS_ST);
  const float vmaxf = SF[ST_VMF + e];
  const float sume = SF[ST_SE + e];
  const u32* sel = (const u32*)(wsc + WS_SEL) + (size_t)((e << 2) + b) * CAP + slot0;
  const float* aff = (const float*)(wsc + WS_AFF) + (size_t)e * NT;
  const float* w1e = (const float*)(wsc + WS_W1E) + (size_t)((e << 2) + b) * (KIN * HID);
  const float* w2e = (const float*)(wsc + WS_W2E) + (size_t)((e << 2) + b) * (HID * CO);
  float* wsums = (float*)(wsc + WS_WS);

  __shared__ SmemU sm;
  __shared__ int tks[128];
  __shared__ float gs[128];

  const int tid = threadIdx.x;
  if (tid < 128) {
    int tok = 0; float g = 0.f;
    if (tid < valid) {
      tok = (int)sel[tid];
      g = expf(aff[tok] - vmaxf) / sume;
    }
    tks[tid] = tok; gs[tid] = g;
  }
  __syncthreads();

  const int m_st = tid & 127, half = tid >> 7;   // staging roles
  const int tm = tid >> 4, tn = tid & 15;        // compute roles
  const size_t xrow = (size_t)tks[m_st] * CI;
  const float bandf = (float)b;

  // ---- phase 1 prologue: stage chunk0 (k 0..31) ----
  {
    const float* xr = x + xrow + half * 16;
    const float4 v0 = *(const float4*)(xr);
    const float4 v1 = *(const float4*)(xr + 4);
    const float4 v2 = *(const float4*)(xr + 8);
    const float4 v3 = *(const float4*)(xr + 12);
    float* Ad = sm.p1.A;
    const int kb = half * 16;
    Ad[(kb+0)*128+m_st]=v0.x; Ad[(kb+1)*128+m_st]=v0.y; Ad[(kb+2)*128+m_st]=v0.z; Ad[(kb+3)*128+m_st]=v0.w;
    Ad[(kb+4)*128+m_st]=v1.x; Ad[(kb+5)*128+m_st]=v1.y; Ad[(kb+6)*128+m_st]=v1.z; Ad[(kb+7)*128+m_st]=v1.w;
    Ad[(kb+8)*128+m_st]=v2.x; Ad[(kb+9)*128+m_st]=v2.y; Ad[(kb+10)*128+m_st]=v2.z; Ad[(kb+11)*128+m_st]=v2.w;
    Ad[(kb+12)*128+m_st]=v3.x; Ad[(kb+13)*128+m_st]=v3.y; Ad[(kb+14)*128+m_st]=v3.z; Ad[(kb+15)*128+m_st]=v3.w;
    for (int i = tid; i < 1536; i += 256)
      *(float4*)&sm.p1.B[i * 4] = *(const float4*)(w1e + i * 4);
  }
  __syncthreads();

  float acc[8][12];
  #pragma unroll
  for (int mi = 0; mi < 8; ++mi)
    #pragma unroll
    for (int nj = 0; nj < 12; ++nj) acc[mi][nj] = 0.f;

  // ---- phase 1: K chunks {32,32,33}, issue-early / write-late pipeline ----
  for (int c = 0; c < 3; ++c) {
    const int kc = (c == 2) ? 33 : 32;
    const int buf = c & 1;
    float4 ra0, ra1, ra2, ra3, rb0, rb1, rb2, rb3, rb4, rb5, rbx;
    const bool last = (c == 2);
    if (!last) {
      const int k0n = 32 * (c + 1);
      const float* xr = x + xrow + k0n + half * 16;
      ra0 = *(const float4*)(xr);      ra1 = *(const float4*)(xr + 4);
      ra2 = *(const float4*)(xr + 8);  ra3 = *(const float4*)(xr + 12);
      const float* wb = w1e + k0n * HID;
      rb0 = *(const float4*)(wb + (tid +    0) * 4);
      rb1 = *(const float4*)(wb + (tid +  256) * 4);
      rb2 = *(const float4*)(wb + (tid +  512) * 4);
      rb3 = *(const float4*)(wb + (tid +  768) * 4);
      rb4 = *(const float4*)(wb + (tid + 1024) * 4);
      rb5 = *(const float4*)(wb + (tid + 1280) * 4);
      if (c == 1 && tid < 48) rbx = *(const float4*)(w1e + 96 * HID + tid * 4);
    }
    const float* Ab = sm.p1.A + buf * (33 * 128);
    const float* Bb = sm.p1.B + buf * (33 * 192);
    #pragma unroll 2
    for (int kk = 0; kk < kc; ++kk) {
      const float* Ar = Ab + kk * 128 + (tm << 3);
      const float4 a0 = *(const float4*)(Ar);
      const float4 a1 = *(const float4*)(Ar + 4);
      const float* Br = Bb + kk * 192 + tn * 12;
      const float4 q0 = *(const float4*)(Br);
      const float4 q1 = *(const float4*)(Br + 4);
      const float4 q2 = *(const float4*)(Br + 8);
      const float avv[8] = {a0.x,a0.y,a0.z,a0.w,a1.x,a1.y,a1.z,a1.w};
      const float bvv[12] = {q0.x,q0.y,q0.z,q0.w,q1.x,q1.y,q1.z,q1.w,q2.x,q2.y,q2.z,q2.w};
      #pragma unroll
      for (int mi = 0; mi < 8; ++mi)
        #pragma unroll
        for (int nj = 0; nj < 12; ++nj)
          acc[mi][nj] = fmaf(avv[mi], bvv[nj], acc[mi][nj]);
    }
    if (!last) {
      float* Ad = sm.p1.A + (buf ^ 1) * (33 * 128);
      const int kb = half * 16;
      Ad[(kb+0)*128+m_st]=ra0.x; Ad[(kb+1)*128+m_st]=ra0.y; Ad[(kb+2)*128+m_st]=ra0.z; Ad[(kb+3)*128+m_st]=ra0.w;
      Ad[(kb+4)*128+m_st]=ra1.x; Ad[(kb+5)*128+m_st]=ra1.y; Ad[(kb+6)*128+m_st]=ra1.z; Ad[(kb+7)*128+m_st]=ra1.w;
      Ad[(kb+8)*128+m_st]=ra2.x; Ad[(kb+9)*128+m_st]=ra2.y; Ad[(kb+10)*128+m_st]=ra2.z; Ad[(kb+11)*128+m_st]=ra2.w;
      Ad[(kb+12)*128+m_st]=ra3.x; Ad[(kb+13)*128+m_st]=ra3.y; Ad[(kb+14)*128+m_st]=ra3.z; Ad[(kb+15)*128+m_st]=ra3.w;
      float* Bd = sm.p1.B + (buf ^ 1) * (33 * 192);
      *(float4*)&Bd[(tid +    0) * 4] = rb0;  *(float4*)&Bd[(tid +  256) * 4] = rb1;
      *(float4*)&Bd[(tid +  512) * 4] = rb2;  *(float4*)&Bd[(tid +  768) * 4] = rb3;
      *(float4*)&Bd[(tid + 1024) * 4] = rb4;  *(float4*)&Bd[(tid + 1280) * 4] = rb5;
      if (c == 1) {
        if (tid < 48) *(float4*)&Bd[32 * 192 + tid * 4] = rbx;
        if (tid < 128) Ad[32 * 128 + tid] = bandf;   // band feature row (k=96)
      }
    }
    __syncthreads();
  }

  // ---- epilogue 1: bias + GELU -> swizzled hT ----
  {
    const float* b1p = eb1 + e * HID + tn * 12;
    float b1v[12];
    #pragma unroll
    for (int nj = 0; nj < 12; ++nj) b1v[nj] = b1p[nj];
    #pragma unroll
    for (int nj = 0; nj < 12; ++nj) {
      const int n = tn * 12 + nj;
      const int sz = ((n ^ (n >> 3)) & 7) << 2;
      float4 h0, h1;
      h0.x = gelu_f(acc[0][nj] + b1v[nj]); h0.y = gelu_f(acc[1][nj] + b1v[nj]);
      h0.z = gelu_f(acc[2][nj] + b1v[nj]); h0.w = gelu_f(acc[3][nj] + b1v[nj]);
      h1.x = gelu_f(acc[4][nj] + b1v[nj]); h1.y = gelu_f(acc[5][nj] + b1v[nj]);
      h1.z = gelu_f(acc[6][nj] + b1v[nj]); h1.w = gelu_f(acc[7][nj] + b1v[nj]);
      *(float4*)&sm.p2.hT[n * 128 + (((tm << 3)    ) ^ sz)] = h0;
      *(float4*)&sm.p2.hT[n * 128 + (((tm << 3) + 4) ^ sz)] = h1;
    }
  }
  // stage w2 chunk 0 (fresh LDS region, no conflict with hT)
  for (int i = tid; i < 768; i += 256)
    *(float4*)&sm.p2.w2[i * 4] = *(const float4*)(w2e + i * 4);
  __syncthreads();

  // ---- phase 2: out = hT GEMM W2eff, K chunks of 32 ----
  float acc2[8][6];
  #pragma unroll
  for (int mi = 0; mi < 8; ++mi)
    #pragma unroll
    for (int nj = 0; nj < 6; ++nj) acc2[mi][nj] = 0.f;
  const int tm2 = tid >> 4, tn2 = tid & 15;
  for (int c = 0; c < 6; ++c) {
    const int buf = c & 1;
    float4 rw0, rw1, rw2;
    const bool last = (c == 5);
    if (!last) {
      const float* wb = w2e + (c + 1) * 3072;
      rw0 = *(const float4*)(wb + (tid +   0) * 4);
      rw1 = *(const float4*)(wb + (tid + 256) * 4);
      rw2 = *(const float4*)(wb + (tid + 512) * 4);
    }
    const float* Wb = sm.p2.w2 + buf * 3072;
    #pragma unroll 2
    for (int kk = 0; kk < 32; ++kk) {
      const int k2 = c * 32 + kk;
      const int sz = ((k2 ^ (k2 >> 3)) & 7) << 2;
      const float* hr = sm.p2.hT + k2 * 128;
      const float4 a0 = *(const float4*)&hr[((tm2 << 3)    ) ^ sz];
      const float4 a1 = *(const float4*)&hr[((tm2 << 3) + 4) ^ sz];
      const float* wr = Wb + kk * 96 + tn2 * 6;
      const float2 w01 = *(const float2*)(wr);
      const float2 w23 = *(const float2*)(wr + 2);
      const float2 w45 = *(const float2*)(wr + 4);
      const float avv[8] = {a0.x,a0.y,a0.z,a0.w,a1.x,a1.y,a1.z,a1.w};
      const float bvv[6] = {w01.x,w01.y,w23.x,w23.y,w45.x,w45.y};
      #pragma unroll
      for (int mi = 0; mi < 8; ++mi)
        #pragma unroll
        for (int nj = 0; nj < 6; ++nj)
          acc2[mi][nj] = fmaf(avv[mi], bvv[nj], acc2[mi][nj]);
    }
    if (!last) {
      float* Wd = sm.p2.w2 + (buf ^ 1) * 3072;
      *(float4*)&Wd[(tid +   0) * 4] = rw0;
      *(float4*)&Wd[(tid + 256) * 4] = rw1;
      *(float4*)&Wd[(tid + 512) * 4] = rw2;
    }
    __syncthreads();
  }

  // ---- epilogue 2: bias + gate + scatter-add ----
  {
    const float* b2p = eb2 + e * CO + tn2 * 6;
    float b2v[6];
    #pragma unroll
    for (int nj = 0; nj < 6; ++nj) b2v[nj] = b2p[nj];
    #pragma unroll
    for (int mi = 0; mi < 8; ++mi) {
      const int m = (tm2 << 3) + mi;
      const float g = gs[m];
      if (g > 0.f) {
        float* orow = dout + (size_t)tks[m] * CO + tn2 * 6;
        #pragma unroll
        for (int nj = 0; nj < 6; ++nj)
          unsafeAtomicAdd(&orow[nj], (acc2[mi][nj] + b2v[nj]) * g);
      }
    }
    if (tn2 == 0) {
      #pragma unroll
      for (int mi = 0; mi < 8; ++mi) {
        const int m = (tm2 << 3) + mi;
        const float g = gs[m];
        if (g > 0.f) unsafeAtomicAdd(&wsums[tks[m]], g);
      }
    }
  }
}

// -------- final: skip projection + normalize aggregated (in place) --------
__global__ __launch_bounds__(256) void k_skip(const float* __restrict__ x,
    const float* __restrict__ skW, const float* __restrict__ skb,
    const char* __restrict__ wsc, float* __restrict__ dout) {
  const int t = blockIdx.x * 256 + threadIdx.x;
  float o[96];
  #pragma unroll
  for (int i = 0; i < 96; ++i) o[i] = skb[i];
  const float* xr = x + (size_t)t * CI;
  for (int c = 0; c < 96; c += 4) {
    const float4 xv = *(const float4*)(xr + c);
    const float xs[4] = {xv.x, xv.y, xv.z, xv.w};
    #pragma unroll
    for (int jj = 0; jj < 4; ++jj) {
      const float xc = xs[jj];
      const float* w = skW + (c + jj) * 96;
      #pragma unroll
      for (int i = 0; i < 96; ++i) o[i] = fmaf(xc, w[i], o[i]);
    }
  }
  const float w = ((const float*)(wsc + WS_WS))[t];
  const float inv = 1.f / (w + 1e-6f);
  float* orow = dout + (size_t)t * 96;
  for (int i = 0; i < 96; i += 4) {
    float4 a = *(float4*)&orow[i];
    a.x = fmaf(a.x, inv, o[i + 0]);
    a.y = fmaf(a.y, inv, o[i + 1]);
    a.z = fmaf(a.z, inv, o[i + 2]);
    a.w = fmaf(a.w, inv, o[i + 3]);
    *(float4*)&orow[i] = a;
  }
}

__global__ void k_loss(const char* __restrict__ wsc, float* __restrict__ dout) {
  if (threadIdx.x == 0 && blockIdx.x == 0) {
    const double s  = *(const double*)(wsc + WS_ST + 448);
    const double s2 = *(const double*)(wsc + WS_ST + 456);
    const double var = (s2 - s * s / (double)NT) / (double)(NT - 1);
    dout[(size_t)NT * CO] = (float)(-log(var + 1e-8) * 0.1);
  }
}

extern "C" void kernel_launch(void* const* d_in, const int* in_sizes, int n_in,
                              void* d_out, int out_size, void* d_ws, size_t ws_size,
                              hipStream_t stream) {
  const float* x   = (const float*)d_in[0];
  const int*   bnd = (const int*)d_in[1];
  const float* Wg  = (const float*)d_in[2];
  const float* lam = (const float*)d_in[3];
  const float* cw1 = (const float*)d_in[4];
  const float* cb1 = (const float*)d_in[5];
  const float* cw2 = (const float*)d_in[6];
  const float* cb2 = (const float*)d_in[7];
  const float* skW = (const float*)d_in[8];
  const float* skb = (const float*)d_in[9];
  const float* eW1 = (const float*)d_in[10];
  const float* eb1 = (const float*)d_in[11];
  const float* eA1 = (const float*)d_in[12];
  const float* eB1 = (const float*)d_in[13];
  const float* eW2 = (const float*)d_in[14];
  const float* eb2 = (const float*)d_in[15];
  const float* eA2 = (const float*)d_in[16];
  const float* eB2 = (const float*)d_in[17];
  float* out = (float*)d_out;
  char* ws = (char*)d_ws;

  hipMemsetAsync(d_out, 0, (size_t)out_size * 4, stream);
  hipMemsetAsync(ws + WS_H1, 0, (size_t)(WS_END - WS_H1), stream);

  k_eff   <<<dim3(32),            dim3(256), 0, stream>>>(eW1, eA1, eB1, eW2, eA2, eB2, ws);
  k_aff   <<<dim3(NT / 256),      dim3(256), 0, stream>>>(x, Wg, lam, cw1, cb1, cw2, cb2, ws);
  k_scan1 <<<dim3(8),             dim3(256), 0, stream>>>(ws);
  k_hist2 <<<dim3(NE * NT / 256), dim3(256), 0, stream>>>(ws);
  k_scan2 <<<dim3(8),             dim3(256), 0, stream>>>(ws);
  k_histI1<<<dim3(NE * NT / 256), dim3(256), 0, stream>>>(ws);
  k_scanI1<<<dim3(8),             dim3(64),  0, stream>>>(ws);
  k_histI2<<<dim3(NE * NT / 256), dim3(256), 0, stream>>>(ws);
  k_scanI2<<<dim3(8),             dim3(64),  0, stream>>>(ws);
  k_compact<<<dim3(NE * NT / 256),dim3(256), 0, stream>>>(bnd, ws);
  k_mlp   <<<dim3(NE * NB * 320), dim3(256), 0, stream>>>(x, eb1, eb2, ws, out);
  k_skip  <<<dim3(NT / 256),      dim3(256), 0, stream>>>(x, skW, skb, ws, out);
  k_loss  <<<dim3(1),             dim3(64),  0, stream>>>(ws, out);
}